// Round 3
// baseline (3323.067 us; speedup 1.0000x reference)
//
#include <hip/hip_runtime.h>
#include <hip/hip_bf16.h>
#include <cmath>

#define DIM 2048
#define NHEADS 16
#define HDIM 128
#define SEQ 2048
#define BATCH 2
#define MTOT (BATCH*SEQ)
#define RMS_EPS 1.1920928955078125e-07f

// ---------------------------------------------------------------------------
// GEMM (NT): C[M,N] = A[M,K] @ B[N,K]^T, all row-major fp32.
// 128x128 tile, BK=16, 256 threads, 8x8 microtile per thread.
// Selects among 3 (B,C) pairs via blockIdx.z so QKV is one launch.
// ---------------------------------------------------------------------------
__global__ __launch_bounds__(256) void gemm_nt_f32(
    const float* __restrict__ A,
    const float* __restrict__ B0, const float* __restrict__ B1, const float* __restrict__ B2,
    float* __restrict__ C0, float* __restrict__ C1, float* __restrict__ C2,
    int M, int N, int K)
{
    const float* B = (blockIdx.z == 0) ? B0 : (blockIdx.z == 1 ? B1 : B2);
    float*       C = (blockIdx.z == 0) ? C0 : (blockIdx.z == 1 ? C1 : C2);

    __shared__ float As[16][132];   // [k][m], pad 132 to de-conflict stores
    __shared__ float Bs[16][132];   // [k][n]

    const int tid = threadIdx.x;
    const int m0 = blockIdx.y * 128;
    const int n0 = blockIdx.x * 128;
    const int lr = tid >> 2;          // 0..63 (loader row)
    const int lc = (tid & 3) << 2;    // 0,4,8,12 (loader k-col)
    const int ty = tid >> 4;          // 0..15
    const int tx = tid & 15;          // 0..15

    float acc[8][8] = {};

    for (int k0 = 0; k0 < K; k0 += 16) {
        float4 a0 = *(const float4*)&A[(size_t)(m0 + lr)      * K + k0 + lc];
        float4 a1 = *(const float4*)&A[(size_t)(m0 + lr + 64) * K + k0 + lc];
        float4 b0 = *(const float4*)&B[(size_t)(n0 + lr)      * K + k0 + lc];
        float4 b1 = *(const float4*)&B[(size_t)(n0 + lr + 64) * K + k0 + lc];
        __syncthreads();   // previous iteration's fragment reads complete
        As[lc+0][lr]    = a0.x; As[lc+1][lr]    = a0.y; As[lc+2][lr]    = a0.z; As[lc+3][lr]    = a0.w;
        As[lc+0][lr+64] = a1.x; As[lc+1][lr+64] = a1.y; As[lc+2][lr+64] = a1.z; As[lc+3][lr+64] = a1.w;
        Bs[lc+0][lr]    = b0.x; Bs[lc+1][lr]    = b0.y; Bs[lc+2][lr]    = b0.z; Bs[lc+3][lr]    = b0.w;
        Bs[lc+0][lr+64] = b1.x; Bs[lc+1][lr+64] = b1.y; Bs[lc+2][lr+64] = b1.z; Bs[lc+3][lr+64] = b1.w;
        __syncthreads();
        #pragma unroll
        for (int kk = 0; kk < 16; ++kk) {
            float a[8], b[8];
            *(float4*)&a[0] = *(const float4*)&As[kk][ty*8];
            *(float4*)&a[4] = *(const float4*)&As[kk][ty*8+4];
            *(float4*)&b[0] = *(const float4*)&Bs[kk][tx*8];
            *(float4*)&b[4] = *(const float4*)&Bs[kk][tx*8+4];
            #pragma unroll
            for (int i = 0; i < 8; ++i)
                #pragma unroll
                for (int j = 0; j < 8; ++j)
                    acc[i][j] = fmaf(a[i], b[j], acc[i][j]);
        }
    }
    #pragma unroll
    for (int i = 0; i < 8; ++i) {
        size_t row = (size_t)(m0 + ty*8 + i);
        float4 o0 = make_float4(acc[i][0], acc[i][1], acc[i][2], acc[i][3]);
        float4 o1 = make_float4(acc[i][4], acc[i][5], acc[i][6], acc[i][7]);
        *(float4*)&C[row * N + n0 + tx*8]     = o0;
        *(float4*)&C[row * N + n0 + tx*8 + 4] = o1;
    }
}

// ---------------------------------------------------------------------------
// Fused RMSNorm (per head, over 128) + RoPE (half-split rotary).
// One wave per (row m, head h). Lane j owns the pair (d=j, d=j+64).
// grid: (MTOT/4, NHEADS, 2[Q,K]); block: 256 = 4 waves.
// ---------------------------------------------------------------------------
__global__ __launch_bounds__(256) void rmsnorm_rope(float* __restrict__ Q,
                                                    float* __restrict__ Kp)
{
    const int wave = threadIdx.x >> 6;
    const int lane = threadIdx.x & 63;
    const int m = blockIdx.x * 4 + wave;          // 0..4095
    const int h = blockIdx.y;
    float* T = blockIdx.z ? Kp : Q;
    const int s = m & (SEQ - 1);                  // position within sequence

    float* row = T + (size_t)m * DIM + h * HDIM;
    float x1 = row[lane];
    float x2 = row[lane + 64];

    float ss = x1*x1 + x2*x2;
    #pragma unroll
    for (int off = 32; off > 0; off >>= 1) ss += __shfl_xor(ss, off);
    const float r = rsqrtf(ss * (1.0f/128.0f) + RMS_EPS);
    x1 *= r; x2 *= r;

    // inv_freq = 1 / base^(2j/128), j = lane
    const float e = (float)lane * (1.0f/64.0f);
    const float inv_freq = 1.0f / powf(10000.0f, e);
    const float fr = (float)s * inv_freq;
    const float c = cosf(fr), sn = sinf(fr);

    row[lane]      =  x1 * c + x2 * sn;
    row[lane + 64] = -x1 * sn + x2 * c;
}

// ---------------------------------------------------------------------------
// Flash-style causal attention, fp32.  TQ=64 q-rows, TK=32 kv-rows per tile.
// 256 threads. Score phase: 16x16 thread grid, 4 rows x 2 cols each.
// PV phase: same rows, 8 d-cols each.  Online softmax in registers.
// K tile XOR-swizzled in LDS (16B units) to break bank conflicts:
//   sw(row) = (row>>1)&7 so that score-phase readers (r0 = tx*2, even)
//   get all 8 bank-quads across tx (row&7 would give only even values -> 4-way).
// grid: (SEQ/64, NHEADS, BATCH)
// ---------------------------------------------------------------------------
__global__ __launch_bounds__(256) void attn_f32(
    const float* __restrict__ Q, const float* __restrict__ Kp,
    const float* __restrict__ V, float* __restrict__ Y)
{
    const int qt = blockIdx.x, h = blockIdx.y, b = blockIdx.z;
    const int tid = threadIdx.x;
    const int ty = tid >> 4, tx = tid & 15;

    __shared__ float Qs[64][HDIM];     // unpadded: reads are wave-broadcast
    __shared__ float Ks[32][HDIM];     // XOR-swizzled in 16B units
    __shared__ float Vs[32][HDIM];     // unpadded: reads contiguous per row
    __shared__ float Ps[64][34];       // pad 34 -> conflict-free broadcast

    const size_t headoff = (size_t)h * HDIM;
    const float* Qbase = Q  + ((size_t)(b*SEQ + qt*64)) * DIM + headoff;
    const float* Kbase = Kp + ((size_t)(b*SEQ)) * DIM + headoff;
    const float* Vbase = V  + ((size_t)(b*SEQ)) * DIM + headoff;

    const float scale = 0.08838834764831845f;  // 1/sqrt(128)

    // stage Q tile (scaled)
    #pragma unroll
    for (int i = 0; i < 8; ++i) {
        int f = tid + i*256;              // 2048 float4s
        int row = f >> 5, c4 = (f & 31) << 2;
        float4 qv = *(const float4*)&Qbase[(size_t)row * DIM + c4];
        qv.x *= scale; qv.y *= scale; qv.z *= scale; qv.w *= scale;
        *(float4*)&Qs[row][c4] = qv;
    }

    float m_i[4], l_i[4], O[4][8];
    #pragma unroll
    for (int i = 0; i < 4; ++i) {
        m_i[i] = -INFINITY; l_i[i] = 0.0f;
        #pragma unroll
        for (int d = 0; d < 8; ++d) O[i][d] = 0.0f;
    }

    const int ntiles = 2*qt + 2;
    for (int kt = 0; kt < ntiles; ++kt) {
        // stage K (swizzled) and V tiles: 32x128 floats each
        float4 kreg[4], vreg[4];
        int rrow[4], rc4[4];
        #pragma unroll
        for (int i = 0; i < 4; ++i) {
            int f = tid + i*256;          // 1024 float4s
            rrow[i] = f >> 5; rc4[i] = f & 31;
            size_t g = (size_t)(kt*32 + rrow[i]) * DIM + (rc4[i] << 2);
            kreg[i] = *(const float4*)&Kbase[g];
            vreg[i] = *(const float4*)&Vbase[g];
        }
        __syncthreads();                   // prior PV reads of Ks/Vs done
        #pragma unroll
        for (int i = 0; i < 4; ++i) {
            int c4s = rc4[i] ^ ((rrow[i] >> 1) & 7);
            *(float4*)&Ks[rrow[i]][c4s << 2] = kreg[i];
            *(float4*)&Vs[rrow[i]][rc4[i] << 2] = vreg[i];
        }
        __syncthreads();

        // ---- scores: sc[i][j] = q(ty*4+i) . k(tx*2+j) ----
        float sc[4][2] = {};
        const int r0 = tx*2, r1 = tx*2 + 1;
        const int sw0 = (r0 >> 1) & 7, sw1 = (r1 >> 1) & 7;
        #pragma unroll
        for (int kd4 = 0; kd4 < 32; ++kd4) {
            float4 k0 = *(const float4*)&Ks[r0][(kd4 ^ sw0) << 2];
            float4 k1 = *(const float4*)&Ks[r1][(kd4 ^ sw1) << 2];
            #pragma unroll
            for (int i = 0; i < 4; ++i) {
                float4 q = *(const float4*)&Qs[ty*4 + i][kd4 << 2];
                sc[i][0] += q.x*k0.x + q.y*k0.y + q.z*k0.z + q.w*k0.w;
                sc[i][1] += q.x*k1.x + q.y*k1.y + q.z*k1.z + q.w*k1.w;
            }
        }

        // ---- online softmax (per q-row; row spread over 16 tx lanes) ----
        const int qg0 = qt*64 + ty*4;
        const int kg0 = kt*32 + tx*2;
        #pragma unroll
        for (int i = 0; i < 4; ++i) {
            const int qg = qg0 + i;
            if (kg0     > qg) sc[i][0] = -INFINITY;
            if (kg0 + 1 > qg) sc[i][1] = -INFINITY;
            float mx = fmaxf(sc[i][0], sc[i][1]);
            #pragma unroll
            for (int off = 1; off < 16; off <<= 1) mx = fmaxf(mx, __shfl_xor(mx, off));
            const float mnew = fmaxf(m_i[i], mx);
            const float alpha = expf(m_i[i] - mnew);   // exp(-inf)=0 first tile
            const float p0 = expf(sc[i][0] - mnew);
            const float p1 = expf(sc[i][1] - mnew);
            float rs = p0 + p1;
            #pragma unroll
            for (int off = 1; off < 16; off <<= 1) rs += __shfl_xor(rs, off);
            l_i[i] = l_i[i]*alpha + rs;
            m_i[i] = mnew;
            #pragma unroll
            for (int d = 0; d < 8; ++d) O[i][d] *= alpha;
            Ps[ty*4 + i][tx*2]     = p0;
            Ps[ty*4 + i][tx*2 + 1] = p1;
        }
        __syncthreads();

        // ---- PV: O[i][d] += sum_kc P[row][kc] * V[kc][tx*8+d] ----
        #pragma unroll 4
        for (int kc = 0; kc < 32; ++kc) {
            float4 v0 = *(const float4*)&Vs[kc][tx*8];
            float4 v1 = *(const float4*)&Vs[kc][tx*8 + 4];
            #pragma unroll
            for (int i = 0; i < 4; ++i) {
                const float p = Ps[ty*4 + i][kc];
                O[i][0] = fmaf(p, v0.x, O[i][0]);
                O[i][1] = fmaf(p, v0.y, O[i][1]);
                O[i][2] = fmaf(p, v0.z, O[i][2]);
                O[i][3] = fmaf(p, v0.w, O[i][3]);
                O[i][4] = fmaf(p, v1.x, O[i][4]);
                O[i][5] = fmaf(p, v1.y, O[i][5]);
                O[i][6] = fmaf(p, v1.z, O[i][6]);
                O[i][7] = fmaf(p, v1.w, O[i][7]);
            }
        }
        __syncthreads();
    }

    // ---- epilogue: normalize and store to Y[b,s, h*128+d] ----
    // Y may alias Q: this block's Q rows were fully consumed into LDS above.
    #pragma unroll
    for (int i = 0; i < 4; ++i) {
        const float inv = 1.0f / l_i[i];
        const size_t row = (size_t)(b*SEQ + qt*64 + ty*4 + i);
        float4 o0 = make_float4(O[i][0]*inv, O[i][1]*inv, O[i][2]*inv, O[i][3]*inv);
        float4 o1 = make_float4(O[i][4]*inv, O[i][5]*inv, O[i][6]*inv, O[i][7]*inv);
        *(float4*)&Y[row * DIM + headoff + tx*8]     = o0;
        *(float4*)&Y[row * DIM + headoff + tx*8 + 4] = o1;
    }
}

// ---------------------------------------------------------------------------
extern "C" void kernel_launch(void* const* d_in, const int* in_sizes, int n_in,
                              void* d_out, int out_size, void* d_ws, size_t ws_size,
                              hipStream_t stream)
{
    const float* x  = (const float*)d_in[0];
    const float* Wq = (const float*)d_in[1];
    const float* Wk = (const float*)d_in[2];
    const float* Wv = (const float*)d_in[3];
    const float* Wo = (const float*)d_in[4];
    float* out = (float*)d_out;

    // Workspace: 3 buffers of 32 MB (Q, K, V). Attention output Y aliases Q
    // (each attn block stages its Q rows to LDS before writing the same rows).
    float* Qb = (float*)d_ws;
    float* Kb = Qb + (size_t)MTOT * DIM;
    float* Vb = Kb + (size_t)MTOT * DIM;
    float* Yb = Qb;

    dim3 blk(256);
    // QKV projections (one launch, z selects W/out)
    gemm_nt_f32<<<dim3(DIM/128, MTOT/128, 3), blk, 0, stream>>>(
        x, Wq, Wk, Wv, Qb, Kb, Vb, MTOT, DIM, DIM);
    // fused RMSNorm + RoPE on Q and K
    rmsnorm_rope<<<dim3(MTOT/4, NHEADS, 2), blk, 0, stream>>>(Qb, Kb);
    // causal flash attention (Y aliases Q)
    attn_f32<<<dim3(SEQ/64, NHEADS, BATCH), blk, 0, stream>>>(Qb, Kb, Vb, Yb);
    // output projection
    gemm_nt_f32<<<dim3(DIM/128, MTOT/128, 1), blk, 0, stream>>>(
        Yb, Wo, Wo, Wo, out, out, out, MTOT, DIM, DIM);
}